// Round 1
// baseline (1175.840 us; speedup 1.0000x reference)
//
#include <hip/hip_runtime.h>
#include <math.h>

#define HH 256
#define WW 256
#define HW (HH*WW)
#define CCH 64

// ---------- tiny transpose: w[O][CK] -> wT[CK][O] ----------
__global__ __launch_bounds__(256) void k_transpose(const float* __restrict__ w,
        float* __restrict__ wT, int O, int CK) {
    int i = blockIdx.x * 256 + threadIdx.x;
    if (i < O * CK) {
        int o = i / CK, ck = i - o * CK;
        wT[ck * O + o] = w[i];
    }
}

// ---------- om = conv3x3(x, w_om) + b_om -> [B,27,H,W] ----------
__global__ __launch_bounds__(256) void k_om(const float* __restrict__ x,
        const float* __restrict__ wT, const float* __restrict__ b_om,
        float* __restrict__ om) {
    const int xx = threadIdx.x;
    const int y  = blockIdx.x & (HH - 1);
    const int b  = blockIdx.x >> 8;
    float acc[27];
#pragma unroll
    for (int o = 0; o < 27; ++o) acc[o] = 0.f;
    const float* xb = x + (size_t)b * CCH * HW + y * WW + xx;
    for (int c = 0; c < CCH; ++c) {
        const float* xc = xb + (size_t)c * HW;
        float v[9];
#pragma unroll
        for (int t = 0; t < 9; ++t) {
            int dy = t / 3 - 1, dx = t % 3 - 1;
            int yy = y + dy, xw = xx + dx;
            bool ok = ((unsigned)yy < HH) && ((unsigned)xw < WW);
            v[t] = ok ? xc[dy * WW + dx] : 0.f;
        }
        const float* wp = wT + c * 9 * 27;   // uniform address
#pragma unroll
        for (int t = 0; t < 9; ++t)
#pragma unroll
            for (int o = 0; o < 27; ++o)
                acc[o] = fmaf(v[t], wp[t * 27 + o], acc[o]);
    }
    float* op = om + (size_t)b * 27 * HW + y * WW + xx;
#pragma unroll
    for (int o = 0; o < 27; ++o) op[(size_t)o * HW] = acc[o] + b_om[o];
}

// ---------- modulated deformable conv + bias + BN1 + ReLU -> h1 ----------
__global__ __launch_bounds__(256) void k_dcn(const float* __restrict__ x,
        const float* __restrict__ om, const float* __restrict__ wT,
        const float* __restrict__ bias,
        const float* __restrict__ g, const float* __restrict__ be,
        const float* __restrict__ mu, const float* __restrict__ var,
        float* __restrict__ out) {
    const int xx = threadIdx.x;
    const int y  = blockIdx.x & (HH - 1);
    const int b  = blockIdx.x >> 8;
    float acc[64];
#pragma unroll
    for (int o = 0; o < 64; ++o) acc[o] = 0.f;
    const float* xb  = x + (size_t)b * CCH * HW;
    const float* omp = om + (size_t)b * 27 * HW + y * WW + xx;
    for (int k = 0; k < 9; ++k) {
        const int ky = k / 3 - 1, kx = k % 3 - 1;
        float o1 = omp[(size_t)k * HW];
        float o2 = omp[(size_t)(9 + k) * HW];
        float ml = omp[(size_t)(18 + k) * HW];
        float mask = 1.f / (1.f + expf(-ml));
        float py = (float)(y + ky) + o1;
        float px = (float)(xx + kx) + o2;
        float y0f = floorf(py), x0f = floorf(px);
        float wy1 = py - y0f, wx1 = px - x0f;
        int y0 = (int)y0f, x0i = (int)x0f;
        int y1 = y0 + 1, x1 = x0i + 1;
        float w00 = (1.f - wy1) * (1.f - wx1) * mask;
        float w01 = (1.f - wy1) * wx1 * mask;
        float w10 = wy1 * (1.f - wx1) * mask;
        float w11 = wy1 * wx1 * mask;
        if (!((unsigned)y0  < HH)) { w00 = 0.f; w01 = 0.f; }
        if (!((unsigned)y1  < HH)) { w10 = 0.f; w11 = 0.f; }
        if (!((unsigned)x0i < WW)) { w00 = 0.f; w10 = 0.f; }
        if (!((unsigned)x1  < WW)) { w01 = 0.f; w11 = 0.f; }
        int cy0 = min(max(y0, 0), HH - 1), cy1 = min(max(y1, 0), HH - 1);
        int cx0 = min(max(x0i, 0), WW - 1), cx1 = min(max(x1, 0), WW - 1);
        int i00 = cy0 * WW + cx0, i01 = cy0 * WW + cx1;
        int i10 = cy1 * WW + cx0, i11 = cy1 * WW + cx1;
        for (int c = 0; c < CCH; ++c) {
            const float* xc = xb + (size_t)c * HW;
            float s = w00 * xc[i00] + w01 * xc[i01] + w10 * xc[i10] + w11 * xc[i11];
            const float* wp = wT + (c * 9 + k) * 64;   // uniform address
#pragma unroll
            for (int o = 0; o < 64; ++o)
                acc[o] = fmaf(s, wp[o], acc[o]);
        }
    }
    float* hp = out + (size_t)b * CCH * HW + y * WW + xx;
#pragma unroll
    for (int o = 0; o < 64; ++o) {
        float sc = g[o] * rsqrtf(var[o] + 1e-5f);
        float v = (acc[o] + bias[o] - mu[o]) * sc + be[o];
        hp[(size_t)o * HW] = fmaxf(v, 0.f);
    }
}

// ---------- dilated 3x3 conv (dil=2, pad=2) + BN + ReLU ----------
__global__ __launch_bounds__(256) void k_conv(const float* __restrict__ in,
        const float* __restrict__ wT, const float* __restrict__ bias,
        const float* __restrict__ g, const float* __restrict__ be,
        const float* __restrict__ mu, const float* __restrict__ var,
        float* __restrict__ out) {
    const int xx = threadIdx.x;
    const int y  = blockIdx.x & (HH - 1);
    const int b  = blockIdx.x >> 8;
    float acc[64];
#pragma unroll
    for (int o = 0; o < 64; ++o) acc[o] = 0.f;
    const float* ib = in + (size_t)b * CCH * HW + y * WW + xx;
    for (int c = 0; c < CCH; ++c) {
        const float* xc = ib + (size_t)c * HW;
        float v[9];
#pragma unroll
        for (int t = 0; t < 9; ++t) {
            int dy = (t / 3 - 1) * 2, dx = (t % 3 - 1) * 2;
            int yy = y + dy, xw = xx + dx;
            bool ok = ((unsigned)yy < HH) && ((unsigned)xw < WW);
            v[t] = ok ? xc[dy * WW + dx] : 0.f;
        }
        const float* wp = wT + c * 9 * 64;   // uniform address
#pragma unroll
        for (int t = 0; t < 9; ++t)
#pragma unroll
            for (int o = 0; o < 64; ++o)
                acc[o] = fmaf(v[t], wp[t * 64 + o], acc[o]);
    }
    float* hp = out + (size_t)b * CCH * HW + y * WW + xx;
#pragma unroll
    for (int o = 0; o < 64; ++o) {
        float sc = g[o] * rsqrtf(var[o] + 1e-5f);
        float v = (acc[o] + bias[o] - mu[o]) * sc + be[o];
        hp[(size_t)o * HW] = fmaxf(v, 0.f);
    }
}

// ---------- final 3x3 conv (pad=1, 1 out ch) + sigmoid + clip ----------
__global__ __launch_bounds__(256) void k_final(const float* __restrict__ in,
        const float* __restrict__ w3, const float* __restrict__ b3,
        float* __restrict__ out) {
    const int xx = threadIdx.x;
    const int y  = blockIdx.x & (HH - 1);
    const int b  = blockIdx.x >> 8;
    float acc = 0.f;
    const float* ib = in + (size_t)b * CCH * HW + y * WW + xx;
    for (int c = 0; c < CCH; ++c) {
        const float* xc = ib + (size_t)c * HW;
        const float* wp = w3 + c * 9;   // w3[0][c][t], uniform
#pragma unroll
        for (int t = 0; t < 9; ++t) {
            int dy = t / 3 - 1, dx = t % 3 - 1;
            int yy = y + dy, xw = xx + dx;
            float v = (((unsigned)yy < HH) && ((unsigned)xw < WW)) ? xc[dy * WW + dx] : 0.f;
            acc = fmaf(v, wp[t], acc);
        }
    }
    float s = 1.f / (1.f + expf(-(acc + b3[0])));
    out[(size_t)b * HW + y * WW + xx] = fminf(fmaxf(s, 1e-4f), 1.f - 1e-4f);
}

extern "C" void kernel_launch(void* const* d_in, const int* in_sizes, int n_in,
                              void* d_out, int out_size, void* d_ws, size_t ws_size,
                              hipStream_t stream) {
    const float* x     = (const float*)d_in[0];
    const float* w_om  = (const float*)d_in[1];
    const float* b_om  = (const float*)d_in[2];
    const float* w_dcn = (const float*)d_in[3];
    const float* b_dcn = (const float*)d_in[4];
    const float* bn1g = (const float*)d_in[5],  *bn1b = (const float*)d_in[6];
    const float* bn1m = (const float*)d_in[7],  *bn1v = (const float*)d_in[8];
    const float* bn2g = (const float*)d_in[9],  *bn2b = (const float*)d_in[10];
    const float* bn2m = (const float*)d_in[11], *bn2v = (const float*)d_in[12];
    const float* bn3g = (const float*)d_in[13], *bn3b = (const float*)d_in[14];
    const float* bn3m = (const float*)d_in[15], *bn3v = (const float*)d_in[16];
    const float* w_h = (const float*)d_in[17], *b_h = (const float*)d_in[18];
    const float* w_w = (const float*)d_in[19], *b_w = (const float*)d_in[20];
    const float* w3  = (const float*)d_in[21], *b3  = (const float*)d_in[22];
    float* outp = (float*)d_out;

    // workspace layout (floats)
    float* ws = (float*)d_ws;
    const size_t OM   = (size_t)2 * 27 * HW;       // 3,538,944
    const size_t HBUF = (size_t)2 * CCH * HW;      // 8,388,608
    float* om    = ws;
    float* h1    = om + OM;
    float* h2    = h1 + HBUF;
    float* wTom  = h2 + HBUF;                      // 27*576
    float* wTdcn = wTom  + 27 * 576;               // 64*576
    float* wTh   = wTdcn + 64 * 576;
    float* wTw   = wTh   + 64 * 576;

    dim3 blk(256);
    k_transpose<<<(27 * 576 + 255) / 256, blk, 0, stream>>>(w_om,  wTom,  27, 576);
    k_transpose<<<(64 * 576 + 255) / 256, blk, 0, stream>>>(w_dcn, wTdcn, 64, 576);
    k_transpose<<<(64 * 576 + 255) / 256, blk, 0, stream>>>(w_h,   wTh,   64, 576);
    k_transpose<<<(64 * 576 + 255) / 256, blk, 0, stream>>>(w_w,   wTw,   64, 576);

    dim3 grid(2 * HH);  // 512 blocks, one row of 256 px each
    k_om  <<<grid, blk, 0, stream>>>(x, wTom, b_om, om);
    k_dcn <<<grid, blk, 0, stream>>>(x, om, wTdcn, b_dcn, bn1g, bn1b, bn1m, bn1v, h1);
    k_conv<<<grid, blk, 0, stream>>>(h1, wTh, b_h, bn2g, bn2b, bn2m, bn2v, h2);
    k_conv<<<grid, blk, 0, stream>>>(h2, wTw, b_w, bn3g, bn3b, bn3m, bn3v, h1);
    k_final<<<grid, blk, 0, stream>>>(h1, w3, b3, outp);
}